// Round 4
// baseline (611.141 us; speedup 1.0000x reference)
//
#include <hip/hip_runtime.h>

#define B_TOT 4096
#define T_LEN 512
#define DIN   8
#define H_DIM 50
#define KTOT  58     // 50 h + 8 x
#define ROWF  80     // fp32 elems per batch-row in LDS (58 used; 80 spreads banks)

typedef __attribute__((ext_vector_type(4))) float floatx4;

__device__ __forceinline__ float fast_tanh(float v) {
  // tanh(v) = 1 - 2/(1+e^{2v}); abs err ~1e-7
  float e = __expf(2.0f * v);
  return 1.0f - 2.0f * __builtin_amdgcn_rcpf(1.0f + e);
}

// Design: wave-private 4-batch recurrence chains, pure fp32 VALU, NO barriers.
//   4096 batches / 4 per wave = 1024 waves = exactly 1 wave per SIMD chip-wide.
//   Lane = m*16 + i (m = batch 0..3, i = n-slot). Accumulator a covers
//   n = a*16 + i (a=0..3; n>=50 lanes are dead weights = 0).
//   W_hh/W_ih live in 232 VGPRs per lane, loaded once (L2-broadcast across blocks).
//   h state round-trips through a wave-private LDS region: writes scatter
//   h[m][n], reads broadcast h[m][0..57] as float4s. Same-wave DS ordering
//   makes this race-free without any s_barrier; x keeps a depth-3 global
//   prefetch pipeline in registers.
__global__ __launch_bounds__(256, 1) void rnn_fused(
    const float* __restrict__ x, const float* __restrict__ W_ih,
    const float* __restrict__ W_hh, const float* __restrict__ b_ih,
    const float* __restrict__ b_hh, const float* __restrict__ fc_W,
    const float* __restrict__ fc_b, float* __restrict__ out)
{
  // [wave][buf][m][k] : 4 * 2 * 4 * 80 * 4B = 10 KB
  __shared__ __align__(16) float hb[4][2][4][ROWF];

  const int tid  = threadIdx.x;
  const int wv   = tid >> 6;
  const int lane = tid & 63;
  const int m    = lane >> 4;      // batch sub-index 0..3
  const int i    = lane & 15;      // n sub-index 0..15
  const int bb   = blockIdx.x * 16 + wv * 4 + m;   // this lane's batch

  // ---- W into registers: acc a covers n = a*16 + i ------------------------
  float wreg[4][KTOT];
  float bias[4], fcw[4];
#pragma unroll
  for (int a = 0; a < 4; ++a) {
    const int n = a * 16 + i;
    const bool live = (n < H_DIM);
#pragma unroll
    for (int k = 0; k < H_DIM; ++k)
      wreg[a][k] = live ? W_hh[n * H_DIM + k] : 0.f;
#pragma unroll
    for (int d = 0; d < DIN; ++d)
      wreg[a][H_DIM + d] = live ? W_ih[n * DIN + d] : 0.f;
    bias[a] = live ? (b_ih[n] + b_hh[n]) : 0.f;
    fcw[a]  = live ? fc_W[n] : 0.f;
  }

  // ---- zero both h buffers (wave-private region; no barrier needed) -------
  {
    float* zb = &hb[wv][0][0][0];
    for (int z = lane; z < 2 * 4 * ROWF; z += 64) zb[z] = 0.f;
  }

  // ---- x prefetch pipeline (lanes 0..31 stage 4 batches x 8 dims) ---------
  const int xm = lane >> 3;        // 0..3 (lanes < 32)
  const int xd = lane & 7;         // 0..7
  const bool xthr = (lane < 32);
  const float* xp = x +
      ((size_t)(blockIdx.x * 16 + wv * 4 + (xthr ? xm : 0)) * T_LEN) * DIN + xd;
  float px0 = 0.f, px1 = 0.f, px2 = 0.f;
  if (xthr) {
    hb[wv][0][xm][H_DIM + xd] = xp[0];          // x for t = 0
    px0 = xp[DIN]; px1 = xp[2 * DIN]; px2 = xp[3 * DIN];  // t = 1,2,3
  }

  // ---- recurrence ----------------------------------------------------------
  float th0 = 0.f, th1 = 0.f, th2 = 0.f, th3 = 0.f;

  auto body = [&](int t, float* curb, float* nxtb) {
    const float* hr = curb + m * ROWF;
    floatx4 hv[15];                       // k = 0..59 (58..59 pad, unused)
#pragma unroll
    for (int j = 0; j < 15; ++j) hv[j] = *(const floatx4*)(hr + 4 * j);

    float a0 = bias[0], a1 = bias[1], a2 = bias[2], a3 = bias[3];
#pragma unroll
    for (int k = 0; k < KTOT; ++k) {
      const float h = hv[k >> 2][k & 3];  // static indices (full unroll)
      a0 = fmaf(wreg[0][k], h, a0);
      a1 = fmaf(wreg[1][k], h, a1);
      a2 = fmaf(wreg[2][k], h, a2);
      a3 = fmaf(wreg[3][k], h, a3);
    }
    th0 = fast_tanh(a0); th1 = fast_tanh(a1);
    th2 = fast_tanh(a2); th3 = fast_tanh(a3);

    float* hw = nxtb + m * ROWF;
    hw[i]      = th0;                     // n = i
    hw[16 + i] = th1;                     // n = 16+i
    hw[32 + i] = th2;                     // n = 32+i
    if (i < 2) hw[48 + i] = th3;          // n = 48,49 (never touch x slots)

    if (xthr) {                           // stage x for step t+1
      nxtb[xm * ROWF + H_DIM + xd] = px0;
      px0 = px1; px1 = px2;
      int tn = t + 4; if (tn > T_LEN - 1) tn = T_LEN - 1;
      px2 = xp[(size_t)tn * DIN];
    }
  };

  float* b0p = &hb[wv][0][0][0];
  float* b1p = &hb[wv][1][0][0];
  for (int t = 0; t < T_LEN; t += 2) {
    body(t,     b0p, b1p);
    body(t + 1, b1p, b0p);
  }

  // ---- fc readout: reduce over n within each 16-lane group ----------------
  float p = th0 * fcw[0] + th1 * fcw[1] + th2 * fcw[2] + th3 * fcw[3];
  p += __shfl_xor(p, 1);
  p += __shfl_xor(p, 2);
  p += __shfl_xor(p, 4);
  p += __shfl_xor(p, 8);
  if (i == 0) out[bb] = p + fc_b[0];
}

extern "C" void kernel_launch(void* const* d_in, const int* in_sizes, int n_in,
                              void* d_out, int out_size, void* d_ws, size_t ws_size,
                              hipStream_t stream) {
  const float* x    = (const float*)d_in[0];
  const float* W_ih = (const float*)d_in[1];
  const float* W_hh = (const float*)d_in[2];
  const float* b_ih = (const float*)d_in[3];
  const float* b_hh = (const float*)d_in[4];
  const float* fc_W = (const float*)d_in[5];
  const float* fc_b = (const float*)d_in[6];
  rnn_fused<<<dim3(B_TOT / 16), dim3(256), 0, stream>>>(
      x, W_ih, W_hh, b_ih, b_hh, fc_W, fc_b, (float*)d_out);
}

// Round 5
// 528.758 us; speedup vs baseline: 1.1558x; 1.1558x over previous
//
#include <hip/hip_runtime.h>

#define B_TOT 4096
#define T_LEN 512
#define DIN   8
#define H_DIM 50

typedef __attribute__((ext_vector_type(8))) short  short8;   // 8 bf16 (4 VGPRs)
typedef __attribute__((ext_vector_type(4))) float  floatx4;  // MFMA acc

__device__ __forceinline__ ushort f2bf_rne(float f) {
  uint u = __float_as_uint(f);
  u += 0x7FFFu + ((u >> 16) & 1u);
  return (ushort)(u >> 16);
}
__device__ __forceinline__ ushort f2bf_trunc(float f) {
  return (ushort)(__float_as_uint(f) >> 16);
}
__device__ __forceinline__ float bf2f(ushort b) {
  return __uint_as_float(((uint)b) << 16);
}
__device__ __forceinline__ float fast_tanh(float v) {
  // tanh(v) = 1 - 2/(1+e^{2v}); abs err ~1e-7
  float e = __expf(2.0f * v);
  return 1.0f - 2.0f * __builtin_amdgcn_rcpf(1.0f + e);
}

// ---------------------------------------------------------------------------
// Single-wave design: 64-thread block = ONE wave owns 16 batches and ALL four
// 16-col n-tiles of the MFMA. Zero barriers; recurrence ordering is same-wave
// DS ordering (compiler-inserted lgkmcnt). Rationale from measurements:
//   R0 (4 waves + 2 barriers/step): 1100 cy/CU-step  (barrier/skew tax)
//   B=8/B=4 multi-block:            worse (exec-masked issue redundancy)
//   fp32 VALU (232 w/lane):         VGPR spill to scratch (160 < 232)
// Here: B-frags 4 tiles x 4 x short8 = 64 VGPR, 24 MFMA/step, epilogue ~13
// live values/lane -- same total issue as R0's 4 waves but no lockstep.
// ---------------------------------------------------------------------------
// LDS layout (identical numerics to R0): ushort lds[4 * 1152]
//   region (buf*2 + part)*1152, buf = double-buffer 0/1, part 0=hi 1=lo
//   each region: A[m=0..15][k=0..71] bf16, row stride 72 (144 B)
//   k 0..49 = h, 50..57 = x_t, 58..63 = zero (K-pad), 64..71 = bank pad
#define ROWS 72
#define REG  1152

__global__ __launch_bounds__(64, 1) void rnn_fused(
    const float* __restrict__ x, const float* __restrict__ W_ih,
    const float* __restrict__ W_hh, const float* __restrict__ b_ih,
    const float* __restrict__ b_hh, const float* __restrict__ fc_W,
    const float* __restrict__ fc_b, float* __restrict__ out)
{
  __shared__ __align__(16) ushort lds[4 * REG];

  const int lane = threadIdx.x;    // single wave: 0..63
  const int col  = lane & 15;      // MFMA n-within-tile (and A-row m)
  const int kg   = lane >> 4;      // 0..3 k-group
  const int b0   = blockIdx.x * 16;

  // ---- B fragments for all 4 n-tiles (hi/lo split), in VGPRs --------------
  union U8 { ushort u[8]; short8 v; };
  short8 Bh[4][2], Bl[4][2];
  floatx4 biasf[4];
#pragma unroll
  for (int a = 0; a < 4; ++a) {
    const int n = a * 16 + col;
    const bool live = (n < H_DIM);
#pragma unroll
    for (int hf = 0; hf < 2; ++hf) {
      U8 bh, bl;
#pragma unroll
      for (int j = 0; j < 8; ++j) {
        int k = hf * 32 + kg * 8 + j;
        float w = 0.f;
        if (live) {
          if (k < H_DIM)            w = W_hh[n * H_DIM + k];
          else if (k < H_DIM + DIN) w = W_ih[n * DIN + (k - H_DIM)];
        }
        ushort hi = f2bf_rne(w);
        bh.u[j] = hi;
        bl.u[j] = f2bf_trunc(w - bf2f(hi));
      }
      Bh[a][hf] = bh.v;
      Bl[a][hf] = bl.v;
    }
    const float bv = live ? (b_ih[n] + b_hh[n]) : 0.f;
    biasf[a] = {bv, bv, bv, bv};
  }

  // ---- zero LDS (h0 = 0, K-pad = 0) ---------------------------------------
  for (int z = lane; z < 4 * REG; z += 64) lds[z] = 0;

  // ---- x staging: all 64 lanes, 2 rows each (16 rows x 8 dims) ------------
  const int xm = lane >> 3;        // 0..7
  const int xd = lane & 7;         // 0..7
  const float* xpA = x + ((size_t)(b0 + xm)     * T_LEN) * DIN + xd;
  const float* xpB = x + ((size_t)(b0 + 8 + xm) * T_LEN) * DIN + xd;
  {
    float xa = xpA[0], xb = xpB[0];
    ushort ha = f2bf_rne(xa), hb2 = f2bf_rne(xb);
    lds[0 * REG + xm * ROWS + H_DIM + xd]       = ha;
    lds[1 * REG + xm * ROWS + H_DIM + xd]       = f2bf_trunc(xa - bf2f(ha));
    lds[0 * REG + (8 + xm) * ROWS + H_DIM + xd] = hb2;
    lds[1 * REG + (8 + xm) * ROWS + H_DIM + xd] = f2bf_trunc(xb - bf2f(hb2));
  }
  float pA0 = xpA[DIN], pA1 = xpA[2 * DIN];   // x for t=1, t=2
  float pB0 = xpB[DIN], pB1 = xpB[2 * DIN];

  // ---- recurrence (no barriers: single wave) ------------------------------
  auto step = [&](int t, int ph, int pl, int qh, int ql) {
    const int rb = col * ROWS + kg * 8;
    short8 Ah0 = *(const short8*)(lds + ph + rb);
    short8 Ah1 = *(const short8*)(lds + ph + rb + 32);
    short8 Al0 = *(const short8*)(lds + pl + rb);
    short8 Al1 = *(const short8*)(lds + pl + rb + 32);

    floatx4 vsum[4];
#pragma unroll
    for (int a = 0; a < 4; ++a) {
      floatx4 acc = biasf[a];
      acc = __builtin_amdgcn_mfma_f32_16x16x32_bf16(Ah0, Bh[a][0], acc, 0, 0, 0);
      acc = __builtin_amdgcn_mfma_f32_16x16x32_bf16(Ah1, Bh[a][1], acc, 0, 0, 0);
      floatx4 acc2 = {0.f, 0.f, 0.f, 0.f};
      acc2 = __builtin_amdgcn_mfma_f32_16x16x32_bf16(Al0, Bh[a][0], acc2, 0, 0, 0);
      acc2 = __builtin_amdgcn_mfma_f32_16x16x32_bf16(Al1, Bh[a][1], acc2, 0, 0, 0);
      floatx4 accB = {0.f, 0.f, 0.f, 0.f};
      accB = __builtin_amdgcn_mfma_f32_16x16x32_bf16(Ah0, Bl[a][0], accB, 0, 0, 0);
      accB = __builtin_amdgcn_mfma_f32_16x16x32_bf16(Ah1, Bl[a][1], accB, 0, 0, 0);
      vsum[a] = acc + acc2 + accB;
    }

    // epilogue: tanh + hi/lo split + write h_{t+1}. C layout: m=kg*4+r, n.
    // tiles 0..2 fully live (n<=47); tile 3 live only for col<2 (n=48,49).
#pragma unroll
    for (int a = 0; a < 3; ++a) {
      const int n = a * 16 + col;
#pragma unroll
      for (int r = 0; r < 4; ++r) {
        float th = fast_tanh(vsum[a][r]);
        ushort hi = f2bf_rne(th);
        ushort lo = f2bf_trunc(th - bf2f(hi));
        int m = kg * 4 + r;
        lds[qh + m * ROWS + n] = hi;
        lds[ql + m * ROWS + n] = lo;
      }
    }
    if (col < 2) {
      const int n = 48 + col;
#pragma unroll
      for (int r = 0; r < 4; ++r) {
        float th = fast_tanh(vsum[3][r]);
        ushort hi = f2bf_rne(th);
        ushort lo = f2bf_trunc(th - bf2f(hi));
        int m = kg * 4 + r;
        lds[qh + m * ROWS + n] = hi;
        lds[ql + m * ROWS + n] = lo;
      }
    }

    // stage x_{t+1} into q; depth-2 register prefetch
    {
      ushort ha = f2bf_rne(pA0), hb2 = f2bf_rne(pB0);
      lds[qh + xm * ROWS + H_DIM + xd]       = ha;
      lds[ql + xm * ROWS + H_DIM + xd]       = f2bf_trunc(pA0 - bf2f(ha));
      lds[qh + (8 + xm) * ROWS + H_DIM + xd] = hb2;
      lds[ql + (8 + xm) * ROWS + H_DIM + xd] = f2bf_trunc(pB0 - bf2f(hb2));
      pA0 = pA1; pB0 = pB1;
      int tn = t + 3; if (tn > T_LEN - 1) tn = T_LEN - 1;
      pA1 = xpA[(size_t)tn * DIN];
      pB1 = xpB[(size_t)tn * DIN];
    }
  };

  for (int t = 0; t < T_LEN; t += 2) {
    step(t,     0 * REG, 1 * REG, 2 * REG, 3 * REG);  // buf0 -> buf1
    step(t + 1, 2 * REG, 3 * REG, 0 * REG, 1 * REG);  // buf1 -> buf0
  }
  // h_512 in buf0 (hi at 0, lo at REG)

  // ---- fc readout: 4 lanes per batch --------------------------------------
  {
    int m = lane >> 2, kq = lane & 3;
    float accr = 0.f;
    for (int k = kq; k < H_DIM; k += 4) {
      float hv = bf2f(lds[0 * REG + m * ROWS + k]) + bf2f(lds[1 * REG + m * ROWS + k]);
      accr += hv * fc_W[k];
    }
    accr += __shfl_xor(accr, 1);
    accr += __shfl_xor(accr, 2);
    if (kq == 0) out[b0 + m] = accr + fc_b[0];
  }
}

extern "C" void kernel_launch(void* const* d_in, const int* in_sizes, int n_in,
                              void* d_out, int out_size, void* d_ws, size_t ws_size,
                              hipStream_t stream) {
  const float* x    = (const float*)d_in[0];
  const float* W_ih = (const float*)d_in[1];
  const float* W_hh = (const float*)d_in[2];
  const float* b_ih = (const float*)d_in[3];
  const float* b_hh = (const float*)d_in[4];
  const float* fc_W = (const float*)d_in[5];
  const float* fc_b = (const float*)d_in[6];
  rnn_fused<<<dim3(B_TOT / 16), dim3(64), 0, stream>>>(
      x, W_ih, W_hh, b_ih, b_hh, fc_W, fc_b, (float*)d_out);
}

// Round 6
// 321.273 us; speedup vs baseline: 1.9022x; 1.6458x over previous
//
#include <hip/hip_runtime.h>

#define B_TOT 4096
#define T_LEN 512
#define DIN   8
#define H_DIM 50

// Interleaved hi/lo layout: one K=128 bf16 row per batch.
//   k' = 2j   -> hi of value j      (j = 0..49 h, 50..57 x, 58..63 zero pad)
//   k' = 2j+1 -> lo of value j
// Row stride 136 ushorts (272 B = 17*16B: aligned, and 272B % 128B != 0
// keeps the b128 read pattern at R0's known-good 2-way-max aliasing).
// Two buffers (double buffer), no separate hi/lo regions anymore.
#define ROWS_U 136            // ushorts per row
#define ROW_UI 68             // uints per row
#define REG_US 2176           // ushorts per buffer (16 rows)
#define REG_UI 1088           // uints per buffer

typedef __attribute__((ext_vector_type(8))) short  short8;   // 8 bf16
typedef __attribute__((ext_vector_type(4))) float  floatx4;  // MFMA acc

__device__ __forceinline__ ushort f2bf_rne(float f) {
  uint u = __float_as_uint(f);
  u += 0x7FFFu + ((u >> 16) & 1u);
  return (ushort)(u >> 16);
}
__device__ __forceinline__ ushort f2bf_trunc(float f) {
  return (ushort)(__float_as_uint(f) >> 16);
}
__device__ __forceinline__ float bf2f(ushort b) {
  return __uint_as_float(((uint)b) << 16);
}
__device__ __forceinline__ float fast_tanh(float v) {
  // tanh(v) = 1 - 2/(1+e^{2v}); abs err ~1e-7
  float e = __expf(2.0f * v);
  return 1.0f - 2.0f * __builtin_amdgcn_rcpf(1.0f + e);
}

// ---------------------------------------------------------------------------
// R0 structure (4 waves, 16 batches/block, barrier/step) — proven best shape.
// This round attacks the per-CU DS-pipe cost identified from counters:
//   R0: 16 ds_read_b128 + ~52 ds_write_b16/step, with every hi/lo store pair
//   same-bank (regions 2304 B apart) -> 8.4M conflict cycles. ~450-500 cy of
//   serialized DS pipe inside the barrier-to-barrier chain.
// Fix: packed (hi|lo<<16) b32 stores into an interleaved K=128 row. MFMA uses
// two B orders: same-order [hi,lo] -> hiA*hiB + loA*loB, swapped [lo,hi] ->
// hiA*loB + loA*hiB; sum = exact (hiA+loA)(hiB+loB). 8 MFMA/wave (was 6),
// stores 8->4 b32, x-stage 2->1, hi/lo conflict class eliminated.
// ---------------------------------------------------------------------------
__global__ __launch_bounds__(256) void rnn_fused(
    const float* __restrict__ x, const float* __restrict__ W_ih,
    const float* __restrict__ W_hh, const float* __restrict__ b_ih,
    const float* __restrict__ b_hh, const float* __restrict__ fc_W,
    const float* __restrict__ fc_b, float* __restrict__ out)
{
  __shared__ __align__(16) ushort lds[2 * REG_US];
  uint* const lds32 = (uint*)lds;

  const int tid  = threadIdx.x;
  const int lane = tid & 63;
  const int wave = tid >> 6;      // 0..3 -> n-tile
  const int col  = lane & 15;     // MFMA n-within-tile (and A-row m)
  const int kg   = lane >> 4;     // 0..3 k-group
  const int b0   = blockIdx.x * 16;

  // ---- B fragments, two interleave orders, in VGPRs -----------------------
  const int nG = wave * 16 + col;           // this lane's output column
  const bool live = (nG < H_DIM);
  union U8 { ushort u[8]; short8 v; };
  short8 Bs[4], Bw[4];                      // same-order / swapped-order
#pragma unroll
  for (int c = 0; c < 4; ++c) {
    U8 bs, bw;
#pragma unroll
    for (int j2 = 0; j2 < 4; ++j2) {
      const int p = c * 16 + kg * 4 + j2;   // value index 0..63
      float w = 0.f;
      if (live) {
        if (p < H_DIM)            w = W_hh[nG * H_DIM + p];
        else if (p < H_DIM + DIN) w = W_ih[nG * DIN + (p - H_DIM)];
      }
      ushort hi = f2bf_rne(w);
      ushort lo = f2bf_trunc(w - bf2f(hi));
      bs.u[2 * j2]     = hi;  bs.u[2 * j2 + 1] = lo;
      bw.u[2 * j2]     = lo;  bw.u[2 * j2 + 1] = hi;
    }
    Bs[c] = bs.v;
    Bw[c] = bw.v;
  }
  const float bv = live ? (b_ih[nG] + b_hh[nG]) : 0.f;
  const floatx4 biasf = {bv, bv, bv, bv};
  const floatx4 zf    = {0.f, 0.f, 0.f, 0.f};

  // ---- zero both buffers (h0 = 0, pads = 0) -------------------------------
  for (int z = tid; z < 2 * REG_UI; z += 256) lds32[z] = 0;
  __syncthreads();

  // ---- x staging: 128 threads, 1 packed b32 each per step -----------------
  const int xm = tid >> 3;                  // batch row 0..15
  const int xd = tid & 7;                   // d 0..7
  const bool xthr = (tid < 128);
  const float* xp = x + ((size_t)(b0 + (xthr ? xm : 0)) * T_LEN) * DIN + xd;
  float px1 = 0.f, px2 = 0.f, px3 = 0.f;
  if (xthr) {
    float x0 = xp[0];
    ushort hi = f2bf_rne(x0);
    ushort lo = f2bf_trunc(x0 - bf2f(hi));
    lds32[xm * ROW_UI + H_DIM + xd] = (uint)hi | ((uint)lo << 16);
    px1 = xp[8]; px2 = xp[16]; px3 = xp[24];   // prefetch t=1,2,3
  }
  __syncthreads();

  // ---- main recurrence ----------------------------------------------------
  auto step = [&](int t, const ushort* lp, uint* q32) {
    const int rb = col * ROWS_U + kg * 8;
    short8 A0 = *(const short8*)(lp + rb);
    short8 A1 = *(const short8*)(lp + rb + 32);
    short8 A2 = *(const short8*)(lp + rb + 64);
    short8 A3 = *(const short8*)(lp + rb + 96);

    // four independent 2-deep MFMA chains: exact (hiA+loA)*(hiB+loB)
    floatx4 ch0 = biasf;
    ch0 = __builtin_amdgcn_mfma_f32_16x16x32_bf16(A0, Bs[0], ch0, 0, 0, 0);
    ch0 = __builtin_amdgcn_mfma_f32_16x16x32_bf16(A1, Bs[1], ch0, 0, 0, 0);
    floatx4 ch1 = zf;
    ch1 = __builtin_amdgcn_mfma_f32_16x16x32_bf16(A0, Bw[0], ch1, 0, 0, 0);
    ch1 = __builtin_amdgcn_mfma_f32_16x16x32_bf16(A1, Bw[1], ch1, 0, 0, 0);
    floatx4 ch2 = zf;
    ch2 = __builtin_amdgcn_mfma_f32_16x16x32_bf16(A2, Bs[2], ch2, 0, 0, 0);
    ch2 = __builtin_amdgcn_mfma_f32_16x16x32_bf16(A3, Bs[3], ch2, 0, 0, 0);
    floatx4 ch3 = zf;
    ch3 = __builtin_amdgcn_mfma_f32_16x16x32_bf16(A2, Bw[2], ch3, 0, 0, 0);
    ch3 = __builtin_amdgcn_mfma_f32_16x16x32_bf16(A3, Bw[3], ch3, 0, 0, 0);
    floatx4 vsum = (ch0 + ch1) + (ch2 + ch3);

    // epilogue: tanh + packed hi|lo b32 store (C layout: m=kg*4+r, n=nG)
    // store banks: (68m + n) % 32 -> exactly 2-way (free)
    if (live) {
#pragma unroll
      for (int r = 0; r < 4; ++r) {
        float th = fast_tanh(vsum[r]);
        ushort hi = f2bf_rne(th);
        ushort lo = f2bf_trunc(th - bf2f(hi));
        q32[(kg * 4 + r) * ROW_UI + nG] = (uint)hi | ((uint)lo << 16);
      }
    }
    // stage x_{t+1} (packed); rotate depth-3 prefetch pipeline
    if (xthr) {
      ushort hi = f2bf_rne(px1);
      ushort lo = f2bf_trunc(px1 - bf2f(hi));
      q32[xm * ROW_UI + H_DIM + xd] = (uint)hi | ((uint)lo << 16);
      px1 = px2; px2 = px3;
      int tn = t + 4; if (tn > T_LEN - 1) tn = T_LEN - 1;
      px3 = xp[(size_t)tn * DIN];
    }
    __syncthreads();
  };

  for (int t = 0; t < T_LEN; t += 2) {
    step(t,     lds,          lds32 + REG_UI);   // buf0 -> buf1
    step(t + 1, lds + REG_US, lds32);            // buf1 -> buf0
  }
  // h_512 now in buf0

  // ---- fc readout: 4 lanes per batch --------------------------------------
  if (tid < 64) {
    int m = lane >> 2, kq = lane & 3;
    float accr = 0.f;
    for (int k = kq; k < H_DIM; k += 4) {
      uint pk = lds32[m * ROW_UI + k];
      float hv = bf2f((ushort)(pk & 0xFFFFu)) + bf2f((ushort)(pk >> 16));
      accr += hv * fc_W[k];
    }
    accr += __shfl_xor(accr, 1);
    accr += __shfl_xor(accr, 2);
    if (kq == 0) out[b0 + m] = accr + fc_b[0];
  }
}

extern "C" void kernel_launch(void* const* d_in, const int* in_sizes, int n_in,
                              void* d_out, int out_size, void* d_ws, size_t ws_size,
                              hipStream_t stream) {
  const float* x    = (const float*)d_in[0];
  const float* W_ih = (const float*)d_in[1];
  const float* W_hh = (const float*)d_in[2];
  const float* b_ih = (const float*)d_in[3];
  const float* b_hh = (const float*)d_in[4];
  const float* fc_W = (const float*)d_in[5];
  const float* fc_b = (const float*)d_in[6];
  rnn_fused<<<dim3(B_TOT / 16), dim3(256), 0, stream>>>(
      x, W_ih, W_hh, b_ih, b_hh, fc_W, fc_b, (float*)d_out);
}